// Round 9
// baseline (282.133 us; speedup 1.0000x reference)
//
#include <hip/hip_runtime.h>

// RRSVM: per (b,c,h,w) take 3x3 zero-padded window, stable-argsort descending,
// out = sum_r v_sorted[r]*s[c,r]; indices emitted as float-encoded ints.
//
// R9 = R8 with 8 px/thread. Octet shares a row (8 | 56). Gather: 3 rows x
// 10 cols = 2 float4 + 2 edge scalars per row = 12 VMEM per 8 px. Byte-staged
// idx tile: 2048 px * 9 = 18432 B LDS (8 blocks/CU preserved). Rank core
// (R7/R8-verified tie-break) with compare CSE across the 8 overlapping
// windows. Writeback: 18 lane-contiguous NT f4 stores/thread from dword
// reads of the byte tile (conflict-free, R4 lesson respected).

#define B_ 16
#define C_ 128
#define H_ 56
#define W_ 56
#define HW (H_*W_)           // 3136
#define NPIX (B_*C_*H_*W_)   // 6422528
#define BLK 256
#define PXT 8
#define PXB (BLK * PXT)      // 2048 pixels per block region
#define GRID (NPIX / PXB)    // 3136

typedef float v4f __attribute__((ext_vector_type(4)));

__global__ __launch_bounds__(BLK) void rrsvm_kernel(
    const float* __restrict__ x, const float* __restrict__ s,
    float* __restrict__ out, float* __restrict__ idxout)
{
    __shared__ unsigned char lds_idx[PXB * 9];   // 18432 B byte-staged indices
    __shared__ float lds_s[24];                  // <=2 channels x 9 weights

    const int tid  = threadIdx.x;
    const int pixr = blockIdx.x * PXB;
    const int pix0 = pixr + tid * PXT;   // contiguous octet, 32B-aligned
    const int w0   = pix0 % W_;          // in {0,8,...,48} (octet shares a row)
    const int t    = pix0 / W_;
    const int h    = t % H_;
    const int bc   = t / H_;

    // ---- stage s for the (<=2) channels this region touches ----
    const int bcf = pixr / HW;
    const int bcl = (pixr + PXB - 1) / HW;
    if (tid < 18) {
        const int which = (tid >= 9);
        const int bcx   = which ? bcl : bcf;
        lds_s[tid] = s[(bcx & (C_ - 1)) * 9 + tid - which * 9];
    }
    const int sbase = (bc == bcf) ? 0 : 9;

    // ---- gather 3 rows x 10 cols: 2 float4 + 2 clamped edge scalars/row ----
    const float* img = x + (size_t)bc * HW;
    const int r0 = (h > 0)      ? h - 1 : 0;
    const int r2 = (h < H_ - 1) ? h + 1 : H_ - 1;
    const int cl = (w0 > 0)        ? w0 - 1 : 0;
    const int cr = (w0 < W_ - PXT) ? w0 + 8 : W_ - 1;
    const float* p0 = img + r0 * W_;
    const float* p1 = img + h  * W_;
    const float* p2 = img + r2 * W_;

    float T[3][10];
    #pragma unroll
    for (int r = 0; r < 3; ++r) {
        const float* p = (r == 0) ? p0 : (r == 1) ? p1 : p2;
        v4f a = *(const v4f*)(p + w0);
        v4f b = *(const v4f*)(p + w0 + 4);
        T[r][0] = p[cl];
        T[r][1] = a.x; T[r][2] = a.y; T[r][3] = a.z; T[r][4] = a.w;
        T[r][5] = b.x; T[r][6] = b.y; T[r][7] = b.z; T[r][8] = b.w;
        T[r][9] = p[cr];
    }
    const bool rv0 = (h > 0), rv2 = (h < H_ - 1);
    const bool cvL = (w0 > 0), cvR = (w0 < W_ - PXT);
    #pragma unroll
    for (int j = 0; j < 10; ++j) {
        T[0][j] = rv0 ? T[0][j] : 0.0f;
        T[2][j] = rv2 ? T[2][j] : 0.0f;
    }
    T[0][0] = cvL ? T[0][0] : 0.0f;
    T[1][0] = cvL ? T[1][0] : 0.0f;
    T[2][0] = cvL ? T[2][0] : 0.0f;
    T[0][9] = cvR ? T[0][9] : 0.0f;
    T[1][9] = cvR ? T[1][9] : 0.0f;
    T[2][9] = cvR ? T[2][9] : 0.0f;

    __syncthreads();   // lds_s visible

    float oacc[PXT];
    #pragma unroll
    for (int px = 0; px < PXT; ++px) {
        const float v[9] = { T[0][px], T[0][px+1], T[0][px+2],
                             T[1][px], T[1][px+1], T[1][px+2],
                             T[2][px], T[2][px+1], T[2][px+2] };
        // rank_k = #elements placed before k (stable descending; ge on
        // lower-index-first pairs == jnp.argsort(-p) tie-break)
        int rank[9];
        #pragma unroll
        for (int k = 0; k < 9; ++k) rank[k] = 8 - k;
        #pragma unroll
        for (int a = 0; a < 8; ++a)
            #pragma unroll
            for (int b = a + 1; b < 9; ++b) {
                const int g = (v[a] >= v[b]);   // CSE'd across windows
                rank[b] += g;
                rank[a] -= g;
            }
        const int base_b = tid * (PXT * 9) + px * 9;
        float acc = 0.0f;
        #pragma unroll
        for (int k = 0; k < 9; ++k) {
            lds_idx[base_b + rank[k]] = (unsigned char)k;
            acc = fmaf(v[k], lds_s[sbase + rank[k]], acc);
        }
        oacc[px] = acc;
    }
    {
        v4f o0, o1;
        o0.x = oacc[0]; o0.y = oacc[1]; o0.z = oacc[2]; o0.w = oacc[3];
        o1.x = oacc[4]; o1.y = oacc[5]; o1.z = oacc[6]; o1.w = oacc[7];
        __builtin_nontemporal_store(o0, (v4f*)(out + pix0));
        __builtin_nontemporal_store(o1, (v4f*)(out + pix0 + 4));
    }

    __syncthreads();   // all idx bytes staged

    // ---- writeback: dword (tid+256k) = 4 idx bytes -> one f4 store ----
    // 2048*9 B = 4608 dwords = 18 * 256
    const unsigned int* lu = (const unsigned int*)lds_idx;
    v4f* dst = (v4f*)(idxout + (size_t)pixr * 9);
    #pragma unroll
    for (int k = 0; k < 18; ++k) {
        const unsigned int u = lu[tid + 256 * k];
        v4f f;
        f.x = (float)( u        & 0xff);
        f.y = (float)((u >>  8) & 0xff);
        f.z = (float)((u >> 16) & 0xff);
        f.w = (float)((u >> 24)       );
        __builtin_nontemporal_store(f, dst + tid + 256 * k);
    }
}

extern "C" void kernel_launch(void* const* d_in, const int* in_sizes, int n_in,
                              void* d_out, int out_size, void* d_ws, size_t ws_size,
                              hipStream_t stream) {
    const float* x = (const float*)d_in[0];   // [16,128,56,56]
    const float* s = (const float*)d_in[1];   // [128,3,3]
    float* out    = (float*)d_out;            // first NPIX floats
    float* idxout = out + NPIX;               // then NPIX*9 float-encoded ints

    rrsvm_kernel<<<GRID, BLK, 0, stream>>>(x, s, out, idxout);
}

// Round 10
// 274.708 us; speedup vs baseline: 1.0270x; 1.0270x over previous
//
#include <hip/hip_runtime.h>

// RRSVM: per (b,c,h,w) take 3x3 zero-padded window, stable-argsort descending,
// out = sum_r v_sorted[r]*s[c,r]; indices emitted as float-encoded ints.
//
// R10 = R8 (best: 271 us) with ONE change: plain stores instead of
// nontemporal. Harness fills sustain 6.4 TB/s with normal stores +
// L2 write-combining; testing whether the NT path was throttling the
// 257 MB write stream. Everything else identical to R8:
//   - 4 px/thread (R9 proved 8 px hits the VGPR/occupancy cliff)
//   - rank-based core (R6 showed sort network was VALU-bound at 71%)
//   - U8 LDS staging, 9216 B -> 8 blocks/CU (R5: 36.9KB LDS was fatal)
//   - lane-contiguous f4 writeback (R4: direct strided stores are fatal)

#define B_ 16
#define C_ 128
#define H_ 56
#define W_ 56
#define HW (H_*W_)           // 3136
#define NPIX (B_*C_*H_*W_)   // 6422528
#define BLK 256
#define PXT 4
#define PXB (BLK * PXT)      // 1024 pixels per block region
#define GRID (NPIX / PXB)    // 6272

typedef float v4f __attribute__((ext_vector_type(4)));

__global__ __launch_bounds__(BLK) void rrsvm_kernel(
    const float* __restrict__ x, const float* __restrict__ s,
    float* __restrict__ out, float* __restrict__ idxout)
{
    __shared__ unsigned char lds_idx[PXB * 9];   // 9216 B, byte-staged indices
    __shared__ float lds_s[24];                  // <=2 channels x 9 weights

    const int tid  = threadIdx.x;
    const int pixr = blockIdx.x * PXB;
    const int pix0 = pixr + tid * PXT;   // contiguous quad, 16B-aligned
    const int w0   = pix0 % W_;          // in {0,4,...,52} (quad shares a row)
    const int t    = pix0 / W_;
    const int h    = t % H_;
    const int bc   = t / H_;

    // ---- stage s for the (<=2) channels this region touches ----
    const int bcf = pixr / HW;
    const int bcl = (pixr + PXB - 1) / HW;
    if (tid < 18) {
        const int which = (tid >= 9);
        const int bcx   = which ? bcl : bcf;
        lds_s[tid] = s[(bcx & (C_ - 1)) * 9 + tid - which * 9];
    }
    const int sbase = (bc == bcf) ? 0 : 9;

    // ---- gather 3 rows x 6 cols: float4 middle + 2 clamped edge scalars ----
    const float* img = x + (size_t)bc * HW;
    const int r0 = (h > 0)      ? h - 1 : 0;
    const int r2 = (h < H_ - 1) ? h + 1 : H_ - 1;
    const int cl = (w0 > 0)        ? w0 - 1 : 0;
    const int cr = (w0 < W_ - PXT) ? w0 + 4 : W_ - 1;
    const float* p0 = img + r0 * W_;
    const float* p1 = img + h  * W_;
    const float* p2 = img + r2 * W_;

    float T[3][6];
    {
        v4f m0 = *(const v4f*)(p0 + w0);
        v4f m1 = *(const v4f*)(p1 + w0);
        v4f m2 = *(const v4f*)(p2 + w0);
        T[0][0] = p0[cl]; T[0][1] = m0.x; T[0][2] = m0.y; T[0][3] = m0.z; T[0][4] = m0.w; T[0][5] = p0[cr];
        T[1][0] = p1[cl]; T[1][1] = m1.x; T[1][2] = m1.y; T[1][3] = m1.z; T[1][4] = m1.w; T[1][5] = p1[cr];
        T[2][0] = p2[cl]; T[2][1] = m2.x; T[2][2] = m2.y; T[2][3] = m2.z; T[2][4] = m2.w; T[2][5] = p2[cr];
    }
    const bool rv0 = (h > 0), rv2 = (h < H_ - 1);
    const bool cvL = (w0 > 0), cvR = (w0 < W_ - PXT);
    #pragma unroll
    for (int j = 0; j < 6; ++j) {
        T[0][j] = rv0 ? T[0][j] : 0.0f;
        T[2][j] = rv2 ? T[2][j] : 0.0f;
    }
    T[0][0] = cvL ? T[0][0] : 0.0f;
    T[1][0] = cvL ? T[1][0] : 0.0f;
    T[2][0] = cvL ? T[2][0] : 0.0f;
    T[0][5] = cvR ? T[0][5] : 0.0f;
    T[1][5] = cvR ? T[1][5] : 0.0f;
    T[2][5] = cvR ? T[2][5] : 0.0f;

    __syncthreads();   // lds_s visible

    float oacc[PXT];
    #pragma unroll
    for (int px = 0; px < PXT; ++px) {
        const float v[9] = { T[0][px], T[0][px+1], T[0][px+2],
                             T[1][px], T[1][px+1], T[1][px+2],
                             T[2][px], T[2][px+1], T[2][px+2] };
        // rank_k = #elements placed before k (stable descending; ge on
        // lower-index-first pairs == jnp.argsort(-p) tie-break)
        int rank[9];
        #pragma unroll
        for (int k = 0; k < 9; ++k) rank[k] = 8 - k;
        #pragma unroll
        for (int a = 0; a < 8; ++a)
            #pragma unroll
            for (int b = a + 1; b < 9; ++b) {
                const int g = (v[a] >= v[b]);   // CSE'd across windows
                rank[b] += g;
                rank[a] -= g;
            }
        // scatter idx byte (argsort inversion) + weighted sum via s[rank]
        const int base_b = tid * 36 + px * 9;
        float acc = 0.0f;
        #pragma unroll
        for (int k = 0; k < 9; ++k) {
            lds_idx[base_b + rank[k]] = (unsigned char)k;
            acc = fmaf(v[k], lds_s[sbase + rank[k]], acc);
        }
        oacc[px] = acc;
    }
    v4f o; o.x = oacc[0]; o.y = oacc[1]; o.z = oacc[2]; o.w = oacc[3];
    *(v4f*)(out + pix0) = o;

    __syncthreads();   // all idx bytes staged

    // ---- writeback: dword (tid+256k) = 4 idx bytes -> one f4 store ----
    const unsigned int* lu = (const unsigned int*)lds_idx;
    v4f* dst = (v4f*)(idxout + (size_t)pixr * 9);
    #pragma unroll
    for (int k = 0; k < 9; ++k) {
        const unsigned int u = lu[tid + 256 * k];
        v4f f;
        f.x = (float)( u        & 0xff);
        f.y = (float)((u >>  8) & 0xff);
        f.z = (float)((u >> 16) & 0xff);
        f.w = (float)((u >> 24)       );
        dst[tid + 256 * k] = f;
    }
}

extern "C" void kernel_launch(void* const* d_in, const int* in_sizes, int n_in,
                              void* d_out, int out_size, void* d_ws, size_t ws_size,
                              hipStream_t stream) {
    const float* x = (const float*)d_in[0];   // [16,128,56,56]
    const float* s = (const float*)d_in[1];   // [128,3,3]
    float* out    = (float*)d_out;            // first NPIX floats
    float* idxout = out + NPIX;               // then NPIX*9 float-encoded ints

    rrsvm_kernel<<<GRID, BLK, 0, stream>>>(x, s, out, idxout);
}